// Round 1
// baseline (215.564 us; speedup 1.0000x reference)
//
#include <hip/hip_runtime.h>

// Problem constants (from reference): N=128, T=2048, D=88
#define NN 128
#define TT 2048
#define DD 88
#define BLOCKS_PER_N 32
#define ROWS_PER_BLOCK (TT / BLOCKS_PER_N)  // 64 rows (timesteps) per block

// Kernel 1: per (n,t) row of D=88 elements, compute
//   fpfn[n*T+t] = #(pred != target)   (false_pos + false_neg for that timestep)
// and per-block partial of tp = #(pred && target), written deterministically
// to tp_part[blockIdx.x]. pred = (output > 0) == (sigmoid(output) > 0.5).
__global__ __launch_bounds__(256) void acc_rowstats_kernel(
    const float* __restrict__ out, const float* __restrict__ tgt,
    float* __restrict__ fpfn, float* __restrict__ tp_part) {
  const int blk = blockIdx.x;
  const int n = blk / BLOCKS_PER_N;
  const int chunk = blk % BLOCKS_PER_N;
  const int t0 = chunk * ROWS_PER_BLOCK;
  const int lane = threadIdx.x & 63;
  const int wave = threadIdx.x >> 6;  // 4 waves per block

  float tp_acc = 0.f;
  for (int r = wave; r < ROWS_PER_BLOCK; r += 4) {
    const int t = t0 + r;
    const size_t base = ((size_t)n * TT + t) * DD;
    float fpfn_l = 0.f, tp_l = 0.f;
    {
      const float o = out[base + lane];
      const float g = tgt[base + lane];
      const bool p = o > 0.f;
      const bool gg = g > 0.5f;
      tp_l += (p && gg) ? 1.f : 0.f;
      fpfn_l += (p != gg) ? 1.f : 0.f;
    }
    if (lane < (DD - 64)) {  // remaining 24 elements of the row
      const float o = out[base + 64 + lane];
      const float g = tgt[base + 64 + lane];
      const bool p = o > 0.f;
      const bool gg = g > 0.5f;
      tp_l += (p && gg) ? 1.f : 0.f;
      fpfn_l += (p != gg) ? 1.f : 0.f;
    }
    // wave-wide (64 lane) reduction of fpfn for this row
    for (int off = 32; off > 0; off >>= 1)
      fpfn_l += __shfl_down(fpfn_l, off, 64);
    if (lane == 0) fpfn[(size_t)n * TT + t] = fpfn_l;
    tp_acc += tp_l;
  }
  // reduce tp across the wave, then across the 4 waves in the block
  for (int off = 32; off > 0; off >>= 1)
    tp_acc += __shfl_down(tp_acc, off, 64);
  __shared__ float s_tp[4];
  if (lane == 0) s_tp[wave] = tp_acc;
  __syncthreads();
  if (threadIdx.x == 0)
    tp_part[blk] = s_tp[0] + s_tp[1] + s_tp[2] + s_tp[3];
}

// Kernel 2: one block per n. Computes T_i, total tp, then
// acc[n] = (sum_{t<T_i} tp/(tp+fpfn[n,t])) / T_i, atomicAdd into out[0].
__global__ __launch_bounds__(256) void acc_finalize_kernel(
    const int* __restrict__ mask, const float* __restrict__ fpfn,
    const float* __restrict__ tp_part, float* __restrict__ out) {
  const int n = blockIdx.x;
  const int tid = threadIdx.x;
  __shared__ float sred[256];
  __shared__ float s_tp, s_ti;

  // T_i = sum of mask row
  int ti = 0;
  for (int t = tid; t < TT; t += 256) ti += mask[n * TT + t];
  sred[tid] = (float)ti;
  __syncthreads();
  for (int s = 128; s > 0; s >>= 1) {
    if (tid < s) sred[tid] += sred[tid + s];
    __syncthreads();
  }
  if (tid == 0) s_ti = sred[0];
  __syncthreads();

  // total tp for this n (32 deterministic partials)
  float tpv = (tid < BLOCKS_PER_N) ? tp_part[n * BLOCKS_PER_N + tid] : 0.f;
  sred[tid] = tpv;
  __syncthreads();
  for (int s = 128; s > 0; s >>= 1) {
    if (tid < s) sred[tid] += sred[tid + s];
    __syncthreads();
  }
  if (tid == 0) s_tp = sred[0];
  __syncthreads();

  const float tp = s_tp;
  const int Ti = (int)s_ti;

  // ratio sum over valid timesteps
  float acc = 0.f;
  for (int t = tid; t < Ti; t += 256) {
    const float denom = tp + fpfn[(size_t)n * TT + t];
    acc += tp / denom;
  }
  sred[tid] = acc;
  __syncthreads();
  for (int s = 128; s > 0; s >>= 1) {
    if (tid < s) sred[tid] += sred[tid + s];
    __syncthreads();
  }
  if (tid == 0) atomicAdd(out, sred[0] / s_ti);
}

extern "C" void kernel_launch(void* const* d_in, const int* in_sizes, int n_in,
                              void* d_out, int out_size, void* d_ws, size_t ws_size,
                              hipStream_t stream) {
  const float* output = (const float*)d_in[0];
  const float* target = (const float*)d_in[1];
  const int* mask = (const int*)d_in[2];
  float* out = (float*)d_out;

  // workspace layout: tp_part[N*BLOCKS_PER_N] then fpfn[N*T]  (~1.06 MB total)
  float* tp_part = (float*)d_ws;
  float* fpfn = tp_part + NN * BLOCKS_PER_N;

  // d_out is poisoned to 0xAA before every timed launch — zero it (async, capture-safe)
  hipMemsetAsync(d_out, 0, sizeof(float) * out_size, stream);

  acc_rowstats_kernel<<<NN * BLOCKS_PER_N, 256, 0, stream>>>(output, target, fpfn, tp_part);
  acc_finalize_kernel<<<NN, 256, 0, stream>>>(mask, fpfn, tp_part, out);
}

// Round 2
// 208.314 us; speedup vs baseline: 1.0348x; 1.0348x over previous
//
#include <hip/hip_runtime.h>

// Problem constants: N=128, T=2048, D=88
#define NN 128
#define TT 2048
#define DD 88
#define ROWS_PER_BLK 128
#define F4_PER_ROW 22                      // 88 floats = 22 float4, rows 16B-aligned
#define F4_PER_TILE (ROWS_PER_BLK * F4_PER_ROW)  // 2816 = 11 * 256
#define K1_BLOCKS (NN * TT / ROWS_PER_BLK)       // 2048, n-aligned (16 blocks per n)

// K1: coalesced float4 streaming. Per float4 (one per (row, 4-elem group)):
//   lds_x[f] = #(pred != target) within the 4 elems; tp accumulated per thread.
// Phase 2: per-row fpfn from 22 LDS entries; block-reduced tp -> tp_part[blk].
__global__ __launch_bounds__(256) void acc_rowstats_kernel(
    const float* __restrict__ out, const float* __restrict__ tgt,
    float* __restrict__ fpfn, float* __restrict__ tp_part) {
  __shared__ float lds_x[F4_PER_TILE];
  const int tid = threadIdx.x;
  const int blk = blockIdx.x;
  const size_t tile_f4 = (size_t)blk * F4_PER_TILE;
  const float4* __restrict__ o4 = (const float4*)out;
  const float4* __restrict__ g4 = (const float4*)tgt;

  float tp = 0.f;
#pragma unroll
  for (int it = 0; it < 11; ++it) {
    const int f = it * 256 + tid;
    const float4 o = o4[tile_f4 + f];
    const float4 g = g4[tile_f4 + f];
    float x = 0.f;
    {
      const float pf = (o.x > 0.f) ? 1.f : 0.f;
      x += fabsf(pf - g.x);
      tp = fmaf(pf, g.x, tp);
    }
    {
      const float pf = (o.y > 0.f) ? 1.f : 0.f;
      x += fabsf(pf - g.y);
      tp = fmaf(pf, g.y, tp);
    }
    {
      const float pf = (o.z > 0.f) ? 1.f : 0.f;
      x += fabsf(pf - g.z);
      tp = fmaf(pf, g.z, tp);
    }
    {
      const float pf = (o.w > 0.f) ? 1.f : 0.f;
      x += fabsf(pf - g.w);
      tp = fmaf(pf, g.w, tp);
    }
    lds_x[f] = x;
  }
  __syncthreads();

  // Phase 2: row r (0..127) handled by thread pair (2r, 2r+1)
  {
    const int r = tid >> 1;
    const int s = tid & 1;
    float v = 0.f;
#pragma unroll
    for (int i = 0; i < 11; ++i) v += lds_x[r * F4_PER_ROW + s * 11 + i];
    v += __shfl_down(v, 1, 64);
    if (s == 0) fpfn[(size_t)blk * ROWS_PER_BLK + r] = v;
  }

  // tp: wave reduce then cross-wave via LDS
  for (int off = 32; off > 0; off >>= 1) tp += __shfl_down(tp, off, 64);
  __shared__ float s_tp[4];
  const int lane = tid & 63, wave = tid >> 6;
  if (lane == 0) s_tp[wave] = tp;
  __syncthreads();
  if (tid == 0) tp_part[blk] = s_tp[0] + s_tp[1] + s_tp[2] + s_tp[3];
}

// K2: one block per n. Fused (T_i, tp) reduction, then ratio sum, one atomic.
__global__ __launch_bounds__(256) void acc_finalize_kernel(
    const int* __restrict__ mask, const float* __restrict__ fpfn,
    const float* __restrict__ tp_part, float* __restrict__ out) {
  const int n = blockIdx.x;
  const int tid = threadIdx.x;
  __shared__ float sa[256], sb[256];

  // T_i via int4 loads: 2048 ints = 512 int4 = 2 per thread
  const int4* m4 = (const int4*)(mask + (size_t)n * TT);
  int ti = 0;
#pragma unroll
  for (int it = 0; it < 2; ++it) {
    const int4 v = m4[it * 256 + tid];
    ti += v.x + v.y + v.z + v.w;
  }
  // tp partials: 16 per n
  const float tpv = (tid < 16) ? tp_part[n * 16 + tid] : 0.f;

  sa[tid] = (float)ti;
  sb[tid] = tpv;
  __syncthreads();
  for (int s = 128; s > 0; s >>= 1) {
    if (tid < s) { sa[tid] += sa[tid + s]; sb[tid] += sb[tid + s]; }
    __syncthreads();
  }
  const float fTi = sa[0];
  const float tp = sb[0];
  const int Ti = (int)fTi;
  __syncthreads();

  // ratio sum over valid timesteps
  const float* __restrict__ fr = fpfn + (size_t)n * TT;
  float acc = 0.f;
  for (int t = tid; t < Ti; t += 256) acc += tp / (tp + fr[t]);
  sa[tid] = acc;
  __syncthreads();
  for (int s = 128; s > 0; s >>= 1) {
    if (tid < s) sa[tid] += sa[tid + s];
    __syncthreads();
  }
  if (tid == 0) atomicAdd(out, sa[0] / fTi);
}

extern "C" void kernel_launch(void* const* d_in, const int* in_sizes, int n_in,
                              void* d_out, int out_size, void* d_ws, size_t ws_size,
                              hipStream_t stream) {
  const float* output = (const float*)d_in[0];
  const float* target = (const float*)d_in[1];
  const int* mask = (const int*)d_in[2];
  float* out = (float*)d_out;

  // ws layout: tp_part[K1_BLOCKS] then fpfn[N*T]  (~1.03 MB)
  float* tp_part = (float*)d_ws;
  float* fpfn = tp_part + K1_BLOCKS;

  hipMemsetAsync(d_out, 0, sizeof(float) * out_size, stream);
  acc_rowstats_kernel<<<K1_BLOCKS, 256, 0, stream>>>(output, target, fpfn, tp_part);
  acc_finalize_kernel<<<NN, 256, 0, stream>>>(mask, fpfn, tp_part, out);
}